// Round 5
// baseline (376.430 us; speedup 1.0000x reference)
//
#include <hip/hip_runtime.h>

// MsPAM all-MFMA v5.
// Algebra: out = x + gamma*(U@P + bl), U = (Wl@Wv)@x + Wl@bv,
//          P = sum_br softmax_rows(Q^T K_br)  (transposed-softmax semantics).
// v5: rowstats restructured to 64 rows/wave + dist-1 K prefetch (was 1:1
//     MFMA:load, latency-bound at 91 us); pmat gets same prefetch; exp->exp2
//     fold (Wq,bq pre-scaled by log2(e) so softmax uses bare v_exp_f32).
// MFMA 16x16x32 bf16 layouts: A[m=lane&15][k=quad*8+j], B[n=lane&15][k=quad*8+j],
// C/D col=lane&15, row=quad*4+reg.

typedef __attribute__((ext_vector_type(8))) short short8;
typedef __attribute__((ext_vector_type(4))) float f32x4;
#define MFMA_BF16(a,b,c) __builtin_amdgcn_mfma_f32_16x16x32_bf16((a),(b),(c),0,0,0)

#define NN 4096
#define CC 512
#define CQd 64
#define LOG2E 1.4426950408889634f

// ---- workspace byte offsets ------------------------------------------------
#define OFF_WQ   ((size_t)0)          // 64x512 bf16   65536  (pre-scaled by log2e)
#define OFF_WK1  ((size_t)65536)
#define OFF_WK2  ((size_t)131072)
#define OFF_WK3  ((size_t)196608)
#define OFF_WLB  ((size_t)262144)     // Wl bf16 512x512   524288
#define OFF_WVT  ((size_t)786432)     // Wv^T bf16 [i][c]  524288
#define OFF_WU   ((size_t)1310720)    // Wl@Wv bf16 [o][i] 524288
#define OFF_BU   ((size_t)1835008)    // Wl@bv fp32 [512]  2048
#define OFF_QT   ((size_t)1837056)    // [2][4096][64] bf16, 1 MB each
#define OFF_K1T  ((size_t)2885632)
#define OFF_K2T  ((size_t)3934208)
#define OFF_K3T  ((size_t)4982784)
#define OFF_U    ((size_t)6031360)    // U bf16 [2][512][4096]  8 MB
#define OFF_Z    ((size_t)14419968)   // Zpart f32 [16][3][2][4096] = 1,572,864
#define OFF_PT   ((size_t)15992832)   // Pt bf16 [2][4096][4096] 64 MB -> end 83,101,696
// xT/yT/zT bf16 [3][2][4096][512] alias the TAIL of Pt (dead before pmat writes Pt)
#define OFF_XT   ((size_t)57935872)
#define OFF_PART ((size_t)83101696)   // bf16 [2 ksplit][2 b][512][4096] 16 MB -> end 99,878,912

__device__ __forceinline__ unsigned short f2bf(float f) {
    unsigned int u = __float_as_uint(f);
    u = u + 0x7FFFu + ((u >> 16) & 1u);   // RNE
    return (unsigned short)(u >> 16);
}
__device__ __forceinline__ ushort4 pack4(float a, float b, float c, float d) {
    return make_ushort4(f2bf(a), f2bf(b), f2bf(c), f2bf(d));
}
__device__ __forceinline__ float bf2f(unsigned short u) {
    return __uint_as_float(((unsigned int)u) << 16);
}
// async global->LDS, 16B per lane; LDS dest = wave-uniform base + lane*16.
__device__ __forceinline__ void gll16(const void* g, void* l) {
    __builtin_amdgcn_global_load_lds(
        (const __attribute__((address_space(1))) void*)g,
        (__attribute__((address_space(3))) void*)l, 16, 0, 0);
}

// ---------------------------------------------------------------------------
// cast Wq,Wk1,Wk2,Wk3,Wl fp32 -> bf16 (Wq scaled by log2e).  grid (256,5), 256.
// ---------------------------------------------------------------------------
__global__ __launch_bounds__(256) void cast_k(
    const float* __restrict__ s0, const float* __restrict__ s1, const float* __restrict__ s2,
    const float* __restrict__ s3, const float* __restrict__ s4, char* __restrict__ ws)
{
    const int y = blockIdx.y;
    const float* src = (y==0)?s0:(y==1)?s1:(y==2)?s2:(y==3)?s3:s4;
    const size_t off = (y==0)?OFF_WQ:(y==1)?OFF_WK1:(y==2)?OFF_WK2:(y==3)?OFF_WK3:OFF_WLB;
    ushort* dst = (ushort*)(ws + off);
    const int size = (y < 4) ? (CQd*CC) : (CC*CC);
    const float sc = (y == 0) ? LOG2E : 1.0f;
    const int idx = (blockIdx.x * 256 + threadIdx.x) * 4;
    if (idx < size) {
        const float4 v = *(const float4*)(src + idx);
        *(ushort4*)(dst + idx) = pack4(v.x*sc, v.y*sc, v.z*sc, v.w*sc);
    }
}

// ---------------------------------------------------------------------------
// Wv fp32 [c][i] -> WvT bf16 [i][c].  grid (8,8), block 256.
// ---------------------------------------------------------------------------
__global__ __launch_bounds__(256) void wvt_k(const float* __restrict__ Wv, ushort* __restrict__ WvT)
{
    const int i0 = blockIdx.x * 64, c0 = blockIdx.y * 64;
    __shared__ float tile[64][65];
    const int t = threadIdx.x, tr = t >> 6, tc = t & 63;
#pragma unroll
    for (int p = 0; p < 16; ++p) {
        const int r = p * 4 + tr;
        tile[r][tc] = Wv[(size_t)(c0 + r) * CC + i0 + tc];
    }
    __syncthreads();
#pragma unroll
    for (int p = 0; p < 16; ++p) {
        const int ir = p * 4 + tr;
        WvT[(size_t)(i0 + ir) * CC + c0 + tc] = f2bf(tile[tc][ir]);
    }
}

// ---------------------------------------------------------------------------
// transpose x,y,z fp32 [b][c][n] -> bf16 [n][c].  grid (64, 8, 6), block 256.
// ---------------------------------------------------------------------------
__global__ __launch_bounds__(256) void transpose_k(
    const float* __restrict__ x, const float* __restrict__ y, const float* __restrict__ z,
    ushort* __restrict__ xt_base)
{
    const int zi = blockIdx.z;
    const int s = zi >> 1, b = zi & 1;
    const float* src = ((s==0) ? x : (s==1) ? y : z) + (size_t)b * CC * NN;
    ushort* dst = xt_base + (size_t)s * 2 * NN * CC + (size_t)b * NN * CC;
    const int n0 = blockIdx.x * 64, c0 = blockIdx.y * 64;
    __shared__ float tile[64][65];
    const int t = threadIdx.x, tr = t >> 6, tc = t & 63;
#pragma unroll
    for (int p = 0; p < 16; ++p) {
        const int r = p * 4 + tr;
        tile[r][tc] = src[(size_t)(c0 + r) * NN + n0 + tc];
    }
    __syncthreads();
#pragma unroll
    for (int p = 0; p < 16; ++p) {
        const int nr = p * 4 + tr;
        dst[(size_t)(n0 + nr) * CC + c0 + tc] = f2bf(tile[tc][nr]);
    }
}

// ---------------------------------------------------------------------------
// bU = Wl @ bv (fp32).  grid (8), block 256.
// ---------------------------------------------------------------------------
__global__ __launch_bounds__(256) void bu_k(
    const float* __restrict__ Wl, const float* __restrict__ bv, float* __restrict__ bU)
{
    const int o0 = blockIdx.x * 64;
    const int t = threadIdx.x, r = t >> 2, seg = t & 3;
    const float* wp = Wl + (size_t)(o0 + r) * CC + seg * 128;
    const float* vp = bv + seg * 128;
    float s = 0.f;
#pragma unroll 8
    for (int c = 0; c < 128; c += 4) {
        const float4 wv = *(const float4*)(wp + c);
        const float4 bb = *(const float4*)(vp + c);
        s += wv.x*bb.x + wv.y*bb.y + wv.z*bb.z + wv.w*bb.w;
    }
    __shared__ float red[64][4];
    red[r][seg] = s;
    __syncthreads();
    if (t < 64) bU[o0 + t] = red[t][0] + red[t][1] + red[t][2] + red[t][3];
}

// ---------------------------------------------------------------------------
// WU = WlB @ WvT^T  (bf16 out [o][i]).  grid (8,8), block 256, wave 32x32.
// ---------------------------------------------------------------------------
__global__ __launch_bounds__(256) void wlwv_k(
    const ushort* __restrict__ WlB, const ushort* __restrict__ WvT, ushort* __restrict__ WU)
{
    const int n0 = blockIdx.x * 64, o0 = blockIdx.y * 64;
    const int t = threadIdx.x, w = t >> 6, lane = t & 63;
    const int m = lane & 15, q = lane >> 4;
    const int ow = o0 + (w >> 1) * 32, nw = n0 + (w & 1) * 32;

    const ushort* Ap = WlB + (size_t)(ow + m) * CC + q * 8;
    const ushort* Bp = WvT + (size_t)(nw + m) * CC + q * 8;

    f32x4 acc[2][2];
#pragma unroll
    for (int i = 0; i < 2; ++i)
#pragma unroll
        for (int j = 0; j < 2; ++j) acc[i][j] = (f32x4)(0.f);

    short8 ab[2][2], bb[2][2];
    auto ld = [&](int s, int k) {
#pragma unroll
        for (int f = 0; f < 2; ++f) {
            ab[s][f] = *(const short8*)(Ap + (size_t)f * 16 * CC + k);
            bb[s][f] = *(const short8*)(Bp + (size_t)f * 16 * CC + k);
        }
    };
    auto comp = [&](int s) {
#pragma unroll
        for (int mf = 0; mf < 2; ++mf)
#pragma unroll
            for (int nf = 0; nf < 2; ++nf)
                acc[mf][nf] = MFMA_BF16(ab[s][mf], bb[s][nf], acc[mf][nf]);
    };
    ld(0, 0); ld(1, 32);
    for (int i = 0; i < 16; i += 2) {
        comp(0); ld(0, ((i + 2 < 16) ? (i + 2) : 15) * 32);
        comp(1); ld(1, ((i + 3 < 16) ? (i + 3) : 15) * 32);
    }
#pragma unroll
    for (int mf = 0; mf < 2; ++mf)
#pragma unroll
        for (int nf = 0; nf < 2; ++nf) {
            const int col = nw + nf * 16 + m;
#pragma unroll
            for (int rr = 0; rr < 4; ++rr)
                WU[(size_t)(ow + mf * 16 + q * 4 + rr) * CC + col] = f2bf(acc[mf][nf][rr]);
        }
}

// ---------------------------------------------------------------------------
// unified projection: rows of [Q;K1;K2;K3;U] = W @ src(+bias).
// rt 0..3 -> Q/K1/K2/K3 (transposed bf16 out [n][64]); rt 4..11 -> U rows.
// grid (32 n-tiles(128), 12, 2), block 256, wave 64r x 32n, K=512.
// ---------------------------------------------------------------------------
__global__ __launch_bounds__(256) void projU_k(
    const char* __restrict__ ws,
    const float* __restrict__ bq, const float* __restrict__ bk1,
    const float* __restrict__ bk2, const float* __restrict__ bk3)
{
    const int rt = blockIdx.y, b = blockIdx.z, n0 = blockIdx.x * 128;
    const int t = threadIdx.x, w = t >> 6, lane = t & 63;
    const int m = lane & 15, q = lane >> 4;
    const int nw = n0 + w * 32;

    const ushort* W;
    const float* bias;
    int sel;
    ushort* dst;
    if (rt < 4) {
        W    = (const ushort*)(ws + ((rt==0)?OFF_WQ:(rt==1)?OFF_WK1:(rt==2)?OFF_WK2:OFF_WK3));
        bias = (rt==0)?bq:(rt==1)?bk1:(rt==2)?bk2:bk3;
        sel  = (rt==2) ? 1 : (rt==3) ? 2 : 0;
        dst  = (ushort*)(ws + ((rt==0)?OFF_QT:(rt==1)?OFF_K1T:(rt==2)?OFF_K2T:OFF_K3T))
               + (size_t)b * NN * CQd;
    } else {
        W    = (const ushort*)(ws + OFF_WU) + (size_t)(rt - 4) * 64 * CC;
        bias = (const float*)(ws + OFF_BU) + (rt - 4) * 64;
        sel  = 0;
        dst  = (ushort*)(ws + OFF_U) + (size_t)b * CC * NN + (size_t)(rt - 4) * 64 * NN;
    }
    const ushort* Bt = (const ushort*)(ws + OFF_XT) + ((size_t)sel * 2 + b) * NN * CC;
    const float bsc = (rt == 0) ? LOG2E : 1.0f;   // bq joins the exp2 fold

    const ushort* Ap = W + (size_t)m * CC + q * 8;
    const ushort* Bp = Bt + (size_t)(nw + m) * CC + q * 8;

    f32x4 acc[4][2];
#pragma unroll
    for (int i = 0; i < 4; ++i)
#pragma unroll
        for (int j = 0; j < 2; ++j) acc[i][j] = (f32x4)(0.f);

    short8 ab[2][4], bb[2][2];
    auto ld = [&](int s, int k) {
#pragma unroll
        for (int f = 0; f < 4; ++f)
            ab[s][f] = *(const short8*)(Ap + (size_t)f * 16 * CC + k);
#pragma unroll
        for (int g = 0; g < 2; ++g)
            bb[s][g] = *(const short8*)(Bp + (size_t)g * 16 * CC + k);
    };
    auto comp = [&](int s) {
#pragma unroll
        for (int mf = 0; mf < 4; ++mf)
#pragma unroll
            for (int nf = 0; nf < 2; ++nf)
                acc[mf][nf] = MFMA_BF16(ab[s][mf], bb[s][nf], acc[mf][nf]);
    };
    ld(0, 0); ld(1, 32);
    for (int i = 0; i < 16; i += 2) {
        comp(0); ld(0, ((i + 2 < 16) ? (i + 2) : 15) * 32);
        comp(1); ld(1, ((i + 3 < 16) ? (i + 3) : 15) * 32);
    }

    if (rt < 4) {   // transposed: dst[n][r]
#pragma unroll
        for (int mf = 0; mf < 4; ++mf) {
            const int r0 = mf * 16 + q * 4;
            const float b0 = bias[r0]*bsc, b1 = bias[r0+1]*bsc,
                        b2 = bias[r0+2]*bsc, b3 = bias[r0+3]*bsc;
#pragma unroll
            for (int nf = 0; nf < 2; ++nf) {
                const f32x4 v = acc[mf][nf];
                *(ushort4*)(dst + (size_t)(nw + nf*16 + m) * CQd + r0) =
                    pack4(v[0]+b0, v[1]+b1, v[2]+b2, v[3]+b3);
            }
        }
    } else {        // natural: dst[r][n]
#pragma unroll
        for (int mf = 0; mf < 4; ++mf) {
            const int r0 = mf * 16 + q * 4;
#pragma unroll
            for (int rr = 0; rr < 4; ++rr) {
                const float bo = bias[r0 + rr];
#pragma unroll
                for (int nf = 0; nf < 2; ++nf)
                    dst[(size_t)(r0 + rr) * NN + nw + nf*16 + m] = f2bf(acc[mf][nf][rr] + bo);
            }
        }
    }
}

// ---------------------------------------------------------------------------
// rowstats v5: Zpart[p=jq*4+w][br][b][i] = sum_{j slice} exp2(S'_br[i,j]).
// Wave owns 64 i x 32 j, sweeps 8 j-steps of 128; dist-1 double-buffered
// K-fragment prefetch (unit = (step,br): 4 loads, 16 MFMA, 64 exp2/lane).
// grid (64 i-tiles, 4 jq, 2 b), block 256.
// ---------------------------------------------------------------------------
__global__ __launch_bounds__(256) void rowstats_k(
    const ushort* __restrict__ Qt, const ushort* __restrict__ K1t,
    const ushort* __restrict__ K2t, const ushort* __restrict__ K3t,
    float* __restrict__ Zpart)
{
    const int it = blockIdx.x, jq = blockIdx.y, b = blockIdx.z;
    const int t = threadIdx.x, w = t >> 6, lane = t & 63;
    const int m = lane & 15, quad = lane >> 4;
    const int i0 = it * 64;
    const int jbase = jq * 1024 + w * 32;

    const ushort* Qp  = Qt  + (size_t)b * NN * CQd;
    const ushort* Kp0 = K1t + (size_t)b * NN * CQd;
    const ushort* Kp1 = K2t + (size_t)b * NN * CQd;
    const ushort* Kp2 = K3t + (size_t)b * NN * CQd;

    short8 a[4][2];
#pragma unroll
    for (int mf = 0; mf < 4; ++mf) {
        const ushort* ap = Qp + (size_t)(i0 + mf * 16 + m) * CQd + quad * 8;
        a[mf][0] = *(const short8*)ap;
        a[mf][1] = *(const short8*)(ap + 32);
    }

    float z[3][4][4];
#pragma unroll
    for (int br = 0; br < 3; ++br)
#pragma unroll
        for (int mf = 0; mf < 4; ++mf)
#pragma unroll
            for (int r = 0; r < 4; ++r) z[br][mf][r] = 0.f;

    short8 kb[2][2][2];   // [slot][nf][half]
    auto ldk = [&](int slot, int s, int br) {
        const ushort* Kb = (br == 0) ? Kp0 : (br == 1) ? Kp1 : Kp2;
#pragma unroll
        for (int nf = 0; nf < 2; ++nf) {
            const ushort* kp = Kb + (size_t)(jbase + s * 128 + nf * 16 + m) * CQd + quad * 8;
            kb[slot][nf][0] = *(const short8*)kp;
            kb[slot][nf][1] = *(const short8*)(kp + 32);
        }
    };

    ldk(0, 0, 0);
    int slot = 0;
    for (int s8 = 0; s8 < 8; ++s8) {
#pragma unroll
        for (int br = 0; br < 3; ++br) {
            const int ns = (br == 2) ? ((s8 < 7) ? s8 + 1 : 7) : s8;
            const int nb = (br == 2) ? 0 : br + 1;
            ldk(slot ^ 1, ns, nb);
#pragma unroll
            for (int nf = 0; nf < 2; ++nf)
#pragma unroll
                for (int mf = 0; mf < 4; ++mf) {
                    f32x4 sf = MFMA_BF16(a[mf][0], kb[slot][nf][0], (f32x4)(0.f));
                    sf = MFMA_BF16(a[mf][1], kb[slot][nf][1], sf);
                    z[br][mf][0] += exp2f(sf[0]);
                    z[br][mf][1] += exp2f(sf[1]);
                    z[br][mf][2] += exp2f(sf[2]);
                    z[br][mf][3] += exp2f(sf[3]);
                }
            slot ^= 1;
        }
    }

    const int p = jq * 4 + w;
#pragma unroll
    for (int br = 0; br < 3; ++br)
#pragma unroll
        for (int mf = 0; mf < 4; ++mf)
#pragma unroll
            for (int r = 0; r < 4; ++r) {
                float v = z[br][mf][r];
                v += __shfl_xor(v, 1);
                v += __shfl_xor(v, 2);
                v += __shfl_xor(v, 4);
                v += __shfl_xor(v, 8);
                if (m == 0)
                    Zpart[(((size_t)p * 3 + br) * 2 + b) * NN + i0 + mf * 16 + quad * 4 + r] = v;
            }
}

// ---------------------------------------------------------------------------
// pmat v5: Pt[j][i] = sum_br exp2(S'_br[i,j]) / Z_br[i], bf16, dist-1 prefetch
// on the 6 (br,nf) units, per-wave LDS transpose for coalesced stores.
// grid (32 j-tiles of 128, 64 i-tiles of 64, 2 b), block 256.
// ---------------------------------------------------------------------------
__global__ __launch_bounds__(256) void pmat_k(
    const ushort* __restrict__ Qt, const ushort* __restrict__ K1t,
    const ushort* __restrict__ K2t, const ushort* __restrict__ K3t,
    const float* __restrict__ Zpart, ushort* __restrict__ Pt)
{
    const int j0 = blockIdx.x * 128, i0 = blockIdx.y * 64, b = blockIdx.z;
    const int t = threadIdx.x, w = t >> 6, lane = t & 63;
    const int m = lane & 15, quad = lane >> 4;
    const int jw = j0 + w * 32;

    __shared__ float zinv[3][64];
    __shared__ ushort pbuf[4][32][72];
    if (t < 192) {
        const int br = t >> 6, il = t & 63;
        float s = 0.f;
#pragma unroll
        for (int p = 0; p < 16; ++p)
            s += Zpart[(((size_t)p * 3 + br) * 2 + b) * NN + i0 + il];
        zinv[br][il] = 1.f / s;
    }
    __syncthreads();

    const ushort* Qp  = Qt  + (size_t)b * NN * CQd;
    const ushort* Kp0 = K1t + (size_t)b * NN * CQd;
    const ushort* Kp1 = K2t + (size_t)b * NN * CQd;
    const ushort* Kp2 = K3t + (size_t)b * NN * CQd;

    short8 a[4][2];
#pragma unroll
    for (int mf = 0; mf < 4; ++mf) {
        const ushort* ap = Qp + (size_t)(i0 + mf * 16 + m) * CQd + quad * 8;
        a[mf][0] = *(const short8*)ap;
        a[mf][1] = *(const short8*)(ap + 32);
    }

    f32x4 pacc[4][2];
#pragma unroll
    for (int mf = 0; mf < 4; ++mf)
#pragma unroll
        for (int nf = 0; nf < 2; ++nf) pacc[mf][nf] = (f32x4)(0.f);

    short8 kb[2][2];    // [slot][half]
    auto ldk = [&](int slot, int u) {
        const int br = u >> 1, nf = u & 1;
        const ushort* Kb = (br == 0) ? Kp0 : (br == 1) ? Kp1 : Kp2;
        const ushort* kp = Kb + (size_t)(jw + nf * 16 + m) * CQd + quad * 8;
        kb[slot][0] = *(const short8*)kp;
        kb[slot][1] = *(const short8*)(kp + 32);
    };

    ldk(0, 0);
    int slot = 0;
    float rz[4][4];
#pragma unroll
    for (int u = 0; u < 6; ++u) {
        ldk(slot ^ 1, (u < 5) ? u + 1 : 5);
        const int br = u >> 1, nf = u & 1;
        if (nf == 0) {
#pragma unroll
            for (int mf = 0; mf < 4; ++mf)
#pragma unroll
                for (int r = 0; r < 4; ++r)
                    rz[mf][r] = zinv[br][mf * 16 + quad * 4 + r];
        }
#pragma unroll
        for (int mf = 0; mf < 4; ++mf) {
            f32x4 sf = MFMA_BF16(a[mf][0], kb[slot][0], (f32x4)(0.f));
            sf = MFMA_BF16(a[mf][1], kb[slot][1], sf);
            pacc[mf][nf][0] += exp2f(sf[0]) * rz[mf][0];
            pacc[mf][nf][1] += exp2f(sf[1]) * rz[mf][1];
            pacc[mf][nf][2] += exp2f(sf[2]) * rz[mf][2];
            pacc[mf][nf][3] += exp2f(sf[3]) * rz[mf][3];
        }
        slot ^= 1;
    }

#pragma unroll
    for (int mf = 0; mf < 4; ++mf)
#pragma unroll
        for (int nf = 0; nf < 2; ++nf) {
            const f32x4 v = pacc[mf][nf];
            *(ushort4*)&pbuf[w][nf * 16 + m][mf * 16 + quad * 4] = pack4(v[0], v[1], v[2], v[3]);
        }
    ushort* Pb = Pt + (size_t)b * NN * NN;
#pragma unroll
    for (int p = 0; p < 4; ++p) {
        const int row = p * 8 + (lane >> 3);
        const int c16 = lane & 7;
        const uint4 v = *(const uint4*)&pbuf[w][row][c16 * 8];
        *(uint4*)(Pb + (size_t)(jw + row) * NN + i0 + c16 * 8) = v;
    }
}

// ---------------------------------------------------------------------------
// av: Part[h][b][c][j] = (U[:, h-half] @ P[h-half, :]) bf16.  m97 structure:
// 128x128 tile, BK=64, global_load_lds(16B) staging, ds_read_b128 frags.
// grid (32 j, 4 c, 4 = b*2+h), block 256 (4 waves, 64x64 each). LDS 32 KB.
// ---------------------------------------------------------------------------
__global__ __launch_bounds__(256) void av_k(
    const ushort* __restrict__ U, const ushort* __restrict__ Pt,
    ushort* __restrict__ Part)
{
    const int t = threadIdx.x, w = t >> 6, lane = t & 63;
    const int m = lane & 15, q = lane >> 4;
    const int zz = blockIdx.z;
    const int b = zz >> 1, h = zz & 1;
    const int j0 = blockIdx.x * 128;
    const int c0 = blockIdx.y * 128;
    const int k00 = h * 2048;

    __shared__ ushort As[128][64];   // [c-local][k-local]
    __shared__ ushort Bs[128][64];   // [j-local][k-local]

    const ushort* Ub = U + (size_t)b * CC * NN;
    const ushort* Pb = Pt + (size_t)b * NN * NN;

    const int srow = w * 32 + (lane >> 3);
    const int scol = (lane & 7) * 8;
    const ushort* gA = Ub + (size_t)(c0 + srow) * NN + k00 + scol;
    const ushort* gB = Pb + (size_t)(j0 + srow) * NN + k00 + scol;

    const int cw = (w >> 1) * 64, jw = (w & 1) * 64;

    f32x4 acc[4][4];
#pragma unroll
    for (int i = 0; i < 4; ++i)
#pragma unroll
        for (int j = 0; j < 4; ++j) acc[i][j] = (f32x4)(0.f);

    for (int k0 = 0; k0 < 2048; k0 += 64) {
        __syncthreads();
#pragma unroll
        for (int i2 = 0; i2 < 4; ++i2) {
            gll16(gA + (size_t)i2 * 8 * NN + k0, &As[w * 32 + i2 * 8][0]);
            gll16(gB + (size_t)i2 * 8 * NN + k0, &Bs[w * 32 + i2 * 8][0]);
        }
        __syncthreads();
#pragma unroll
        for (int kk = 0; kk < 2; ++kk) {
            short8 af[4], bf[4];
#pragma unroll
            for (int f = 0; f < 4; ++f) {
                af[f] = *(const short8*)&As[cw + f * 16 + m][kk * 32 + q * 8];
                bf[f] = *(const short8*)&Bs[jw + f * 16 + m][kk * 32 + q * 8];
            }
#pragma unroll
            for (int mf = 0; mf < 4; ++mf)
#pragma unroll
                for (int nf = 0; nf < 4; ++nf)
                    acc[mf][nf] = MFMA_BF16(af[mf], bf[nf], acc[mf][nf]);
        }
    }

    ushort* Pp = Part + ((size_t)h * 2 + b) * CC * NN;
#pragma unroll
    for (int mf = 0; mf < 4; ++mf) {
        const int r0 = c0 + cw + mf * 16 + q * 4;
#pragma unroll
        for (int nf = 0; nf < 4; ++nf) {
            const int col = j0 + jw + nf * 16 + m;
            const f32x4 v = acc[mf][nf];
            Pp[(size_t)(r0 + 0) * NN + col] = f2bf(v[0]);
            Pp[(size_t)(r0 + 1) * NN + col] = f2bf(v[1]);
            Pp[(size_t)(r0 + 2) * NN + col] = f2bf(v[2]);
            Pp[(size_t)(r0 + 3) * NN + col] = f2bf(v[3]);
        }
    }
}

// ---------------------------------------------------------------------------
// fin: out = x + gamma*(Part0 + Part1 + bl).  grid (1024 rows, 4), block 256.
// ---------------------------------------------------------------------------
__global__ __launch_bounds__(256) void fin_k(
    const ushort* __restrict__ Part, const float* __restrict__ x,
    const float* __restrict__ bl, const float* __restrict__ gam,
    float* __restrict__ out)
{
    const int row = blockIdx.x;                 // b*512 + c
    const int b = row >> 9, c = row & 511;
    const int col = blockIdx.y * 1024 + threadIdx.x * 4;
    const float g = gam[0];
    const float bo = bl[c];
    const size_t base = ((size_t)b * CC + c) * NN + col;
    const ushort4 p0 = *(const ushort4*)(Part + ((size_t)b * CC + c) * NN + col);
    const ushort4 p1 = *(const ushort4*)(Part + ((size_t)(2 + b) * CC + c) * NN + col);
    const float4 xv = *(const float4*)(x + base);
    float4 o;
    o.x = xv.x + g * (bf2f(p0.x) + bf2f(p1.x) + bo);
    o.y = xv.y + g * (bf2f(p0.y) + bf2f(p1.y) + bo);
    o.z = xv.z + g * (bf2f(p0.z) + bf2f(p1.z) + bo);
    o.w = xv.w + g * (bf2f(p0.w) + bf2f(p1.w) + bo);
    *(float4*)(out + base) = o;
}

// ---------------------------------------------------------------------------
extern "C" void kernel_launch(void* const* d_in, const int* in_sizes, int n_in,
                              void* d_out, int out_size, void* d_ws, size_t ws_size,
                              hipStream_t stream)
{
    (void)in_sizes; (void)n_in; (void)out_size; (void)ws_size;

    const float* xp  = (const float*)d_in[0];
    const float* yp  = (const float*)d_in[1];
    const float* zp  = (const float*)d_in[2];
    const float* Wq  = (const float*)d_in[3];
    const float* bq  = (const float*)d_in[4];
    const float* Wk1 = (const float*)d_in[5];
    const float* bk1 = (const float*)d_in[6];
    const float* Wk2 = (const float*)d_in[7];
    const float* bk2 = (const float*)d_in[8];
    const float* Wk3 = (const float*)d_in[9];
    const float* bk3 = (const float*)d_in[10];
    const float* Wv  = (const float*)d_in[11];
    const float* bv  = (const float*)d_in[12];
    const float* Wl  = (const float*)d_in[13];
    const float* bl  = (const float*)d_in[14];
    const float* gam = (const float*)d_in[15];
    float* out = (float*)d_out;

    char* ws = (char*)d_ws;
    ushort* WVT = (ushort*)(ws + OFF_WVT);
    ushort* WU  = (ushort*)(ws + OFF_WU);
    float*  BU  = (float*)(ws + OFF_BU);
    const ushort* QT  = (const ushort*)(ws + OFF_QT);
    const ushort* K1T = (const ushort*)(ws + OFF_K1T);
    const ushort* K2T = (const ushort*)(ws + OFF_K2T);
    const ushort* K3T = (const ushort*)(ws + OFF_K3T);
    const ushort* Ub  = (const ushort*)(ws + OFF_U);
    float*  ZP  = (float*)(ws + OFF_Z);
    ushort* PT  = (ushort*)(ws + OFF_PT);
    ushort* XT  = (ushort*)(ws + OFF_XT);
    ushort* PRT = (ushort*)(ws + OFF_PART);

    cast_k<<<dim3(256, 5), 256, 0, stream>>>(Wq, Wk1, Wk2, Wk3, Wl, ws);
    wvt_k<<<dim3(8, 8), 256, 0, stream>>>(Wv, WVT);
    transpose_k<<<dim3(64, 8, 6), 256, 0, stream>>>(xp, yp, zp, XT);
    bu_k<<<dim3(8), 256, 0, stream>>>(Wl, bv, BU);
    wlwv_k<<<dim3(8, 8), 256, 0, stream>>>((const ushort*)(ws + OFF_WLB), WVT, WU);
    projU_k<<<dim3(32, 12, 2), 256, 0, stream>>>(ws, bq, bk1, bk2, bk3);
    rowstats_k<<<dim3(64, 4, 2), 256, 0, stream>>>(QT, K1T, K2T, K3T, ZP);
    pmat_k<<<dim3(32, 64, 2), 256, 0, stream>>>(QT, K1T, K2T, K3T, ZP, PT);
    av_k<<<dim3(32, 4, 4), 256, 0, stream>>>(Ub, PT, PRT);
    fin_k<<<dim3(1024, 4), 256, 0, stream>>>(PRT, xp, bl, gam, out);
}

// Round 6
// 317.406 us; speedup vs baseline: 1.1860x; 1.1860x over previous
//
#include <hip/hip_runtime.h>

// MsPAM all-MFMA v6.
// Algebra: out = x + gamma*(U@P + bl), U = (Wl@Wv)@x + Wl@bv,
//          P = sum_br softmax_rows(Q^T K_br)  (transposed-softmax semantics).
// v6: rowstats double-buffer rebuilt with COMPILE-TIME slot indices (v5's
//     runtime `slot^=1` made kb[] runtime-indexed -> scratch spill, 166 MB
//     of spill writes, VGPR=256). Unroll j-steps x2 (6 units, even) and write
//     the 6 ldk/comp calls with literal slots.
// MFMA 16x16x32 bf16 layouts: A[m=lane&15][k=quad*8+j], B[n=lane&15][k=quad*8+j],
// C/D col=lane&15, row=quad*4+reg.

typedef __attribute__((ext_vector_type(8))) short short8;
typedef __attribute__((ext_vector_type(4))) float f32x4;
#define MFMA_BF16(a,b,c) __builtin_amdgcn_mfma_f32_16x16x32_bf16((a),(b),(c),0,0,0)

#define NN 4096
#define CC 512
#define CQd 64
#define LOG2E 1.4426950408889634f

// ---- workspace byte offsets ------------------------------------------------
#define OFF_WQ   ((size_t)0)          // 64x512 bf16   65536  (pre-scaled by log2e)
#define OFF_WK1  ((size_t)65536)
#define OFF_WK2  ((size_t)131072)
#define OFF_WK3  ((size_t)196608)
#define OFF_WLB  ((size_t)262144)     // Wl bf16 512x512   524288
#define OFF_WVT  ((size_t)786432)     // Wv^T bf16 [i][c]  524288
#define OFF_WU   ((size_t)1310720)    // Wl@Wv bf16 [o][i] 524288
#define OFF_BU   ((size_t)1835008)    // Wl@bv fp32 [512]  2048
#define OFF_QT   ((size_t)1837056)    // [2][4096][64] bf16, 1 MB each
#define OFF_K1T  ((size_t)2885632)
#define OFF_K2T  ((size_t)3934208)
#define OFF_K3T  ((size_t)4982784)
#define OFF_U    ((size_t)6031360)    // U bf16 [2][512][4096]  8 MB
#define OFF_Z    ((size_t)14419968)   // Zpart f32 [16][3][2][4096] = 1,572,864
#define OFF_PT   ((size_t)15992832)   // Pt bf16 [2][4096][4096] 64 MB -> end 83,101,696
// xT/yT/zT bf16 [3][2][4096][512] alias the TAIL of Pt (dead before pmat writes Pt)
#define OFF_XT   ((size_t)57935872)
#define OFF_PART ((size_t)83101696)   // bf16 [2 ksplit][2 b][512][4096] 16 MB -> end 99,878,912

__device__ __forceinline__ unsigned short f2bf(float f) {
    unsigned int u = __float_as_uint(f);
    u = u + 0x7FFFu + ((u >> 16) & 1u);   // RNE
    return (unsigned short)(u >> 16);
}
__device__ __forceinline__ ushort4 pack4(float a, float b, float c, float d) {
    return make_ushort4(f2bf(a), f2bf(b), f2bf(c), f2bf(d));
}
__device__ __forceinline__ float bf2f(unsigned short u) {
    return __uint_as_float(((unsigned int)u) << 16);
}
// async global->LDS, 16B per lane; LDS dest = wave-uniform base + lane*16.
__device__ __forceinline__ void gll16(const void* g, void* l) {
    __builtin_amdgcn_global_load_lds(
        (const __attribute__((address_space(1))) void*)g,
        (__attribute__((address_space(3))) void*)l, 16, 0, 0);
}

// ---------------------------------------------------------------------------
// cast Wq,Wk1,Wk2,Wk3,Wl fp32 -> bf16 (Wq scaled by log2e).  grid (256,5), 256.
// ---------------------------------------------------------------------------
__global__ __launch_bounds__(256) void cast_k(
    const float* __restrict__ s0, const float* __restrict__ s1, const float* __restrict__ s2,
    const float* __restrict__ s3, const float* __restrict__ s4, char* __restrict__ ws)
{
    const int y = blockIdx.y;
    const float* src = (y==0)?s0:(y==1)?s1:(y==2)?s2:(y==3)?s3:s4;
    const size_t off = (y==0)?OFF_WQ:(y==1)?OFF_WK1:(y==2)?OFF_WK2:(y==3)?OFF_WK3:OFF_WLB;
    ushort* dst = (ushort*)(ws + off);
    const int size = (y < 4) ? (CQd*CC) : (CC*CC);
    const float sc = (y == 0) ? LOG2E : 1.0f;
    const int idx = (blockIdx.x * 256 + threadIdx.x) * 4;
    if (idx < size) {
        const float4 v = *(const float4*)(src + idx);
        *(ushort4*)(dst + idx) = pack4(v.x*sc, v.y*sc, v.z*sc, v.w*sc);
    }
}

// ---------------------------------------------------------------------------
// Wv fp32 [c][i] -> WvT bf16 [i][c].  grid (8,8), block 256.
// ---------------------------------------------------------------------------
__global__ __launch_bounds__(256) void wvt_k(const float* __restrict__ Wv, ushort* __restrict__ WvT)
{
    const int i0 = blockIdx.x * 64, c0 = blockIdx.y * 64;
    __shared__ float tile[64][65];
    const int t = threadIdx.x, tr = t >> 6, tc = t & 63;
#pragma unroll
    for (int p = 0; p < 16; ++p) {
        const int r = p * 4 + tr;
        tile[r][tc] = Wv[(size_t)(c0 + r) * CC + i0 + tc];
    }
    __syncthreads();
#pragma unroll
    for (int p = 0; p < 16; ++p) {
        const int ir = p * 4 + tr;
        WvT[(size_t)(i0 + ir) * CC + c0 + tc] = f2bf(tile[tc][ir]);
    }
}

// ---------------------------------------------------------------------------
// transpose x,y,z fp32 [b][c][n] -> bf16 [n][c].  grid (64, 8, 6), block 256.
// ---------------------------------------------------------------------------
__global__ __launch_bounds__(256) void transpose_k(
    const float* __restrict__ x, const float* __restrict__ y, const float* __restrict__ z,
    ushort* __restrict__ xt_base)
{
    const int zi = blockIdx.z;
    const int s = zi >> 1, b = zi & 1;
    const float* src = ((s==0) ? x : (s==1) ? y : z) + (size_t)b * CC * NN;
    ushort* dst = xt_base + (size_t)s * 2 * NN * CC + (size_t)b * NN * CC;
    const int n0 = blockIdx.x * 64, c0 = blockIdx.y * 64;
    __shared__ float tile[64][65];
    const int t = threadIdx.x, tr = t >> 6, tc = t & 63;
#pragma unroll
    for (int p = 0; p < 16; ++p) {
        const int r = p * 4 + tr;
        tile[r][tc] = src[(size_t)(c0 + r) * NN + n0 + tc];
    }
    __syncthreads();
#pragma unroll
    for (int p = 0; p < 16; ++p) {
        const int nr = p * 4 + tr;
        dst[(size_t)(n0 + nr) * CC + c0 + tc] = f2bf(tile[tc][nr]);
    }
}

// ---------------------------------------------------------------------------
// bU = Wl @ bv (fp32).  grid (8), block 256.
// ---------------------------------------------------------------------------
__global__ __launch_bounds__(256) void bu_k(
    const float* __restrict__ Wl, const float* __restrict__ bv, float* __restrict__ bU)
{
    const int o0 = blockIdx.x * 64;
    const int t = threadIdx.x, r = t >> 2, seg = t & 3;
    const float* wp = Wl + (size_t)(o0 + r) * CC + seg * 128;
    const float* vp = bv + seg * 128;
    float s = 0.f;
#pragma unroll 8
    for (int c = 0; c < 128; c += 4) {
        const float4 wv = *(const float4*)(wp + c);
        const float4 bb = *(const float4*)(vp + c);
        s += wv.x*bb.x + wv.y*bb.y + wv.z*bb.z + wv.w*bb.w;
    }
    __shared__ float red[64][4];
    red[r][seg] = s;
    __syncthreads();
    if (t < 64) bU[o0 + t] = red[t][0] + red[t][1] + red[t][2] + red[t][3];
}

// ---------------------------------------------------------------------------
// WU = WlB @ WvT^T  (bf16 out [o][i]).  grid (8,8), block 256, wave 32x32.
// ---------------------------------------------------------------------------
__global__ __launch_bounds__(256) void wlwv_k(
    const ushort* __restrict__ WlB, const ushort* __restrict__ WvT, ushort* __restrict__ WU)
{
    const int n0 = blockIdx.x * 64, o0 = blockIdx.y * 64;
    const int t = threadIdx.x, w = t >> 6, lane = t & 63;
    const int m = lane & 15, q = lane >> 4;
    const int ow = o0 + (w >> 1) * 32, nw = n0 + (w & 1) * 32;

    const ushort* Ap = WlB + (size_t)(ow + m) * CC + q * 8;
    const ushort* Bp = WvT + (size_t)(nw + m) * CC + q * 8;

    f32x4 acc[2][2];
#pragma unroll
    for (int i = 0; i < 2; ++i)
#pragma unroll
        for (int j = 0; j < 2; ++j) acc[i][j] = (f32x4)(0.f);

    short8 ab[2][2], bb[2][2];
    auto ld = [&](int s, int k) {
#pragma unroll
        for (int f = 0; f < 2; ++f) {
            ab[s][f] = *(const short8*)(Ap + (size_t)f * 16 * CC + k);
            bb[s][f] = *(const short8*)(Bp + (size_t)f * 16 * CC + k);
        }
    };
    auto comp = [&](int s) {
#pragma unroll
        for (int mf = 0; mf < 2; ++mf)
#pragma unroll
            for (int nf = 0; nf < 2; ++nf)
                acc[mf][nf] = MFMA_BF16(ab[s][mf], bb[s][nf], acc[mf][nf]);
    };
    ld(0, 0); ld(1, 32);
    for (int i = 0; i < 16; i += 2) {
        comp(0); ld(0, ((i + 2 < 16) ? (i + 2) : 15) * 32);
        comp(1); ld(1, ((i + 3 < 16) ? (i + 3) : 15) * 32);
    }
#pragma unroll
    for (int mf = 0; mf < 2; ++mf)
#pragma unroll
        for (int nf = 0; nf < 2; ++nf) {
            const int col = nw + nf * 16 + m;
#pragma unroll
            for (int rr = 0; rr < 4; ++rr)
                WU[(size_t)(ow + mf * 16 + q * 4 + rr) * CC + col] = f2bf(acc[mf][nf][rr]);
        }
}

// ---------------------------------------------------------------------------
// unified projection: rows of [Q;K1;K2;K3;U] = W @ src(+bias).
// rt 0..3 -> Q/K1/K2/K3 (transposed bf16 out [n][64]); rt 4..11 -> U rows.
// grid (32 n-tiles(128), 12, 2), block 256, wave 64r x 32n, K=512.
// ---------------------------------------------------------------------------
__global__ __launch_bounds__(256) void projU_k(
    const char* __restrict__ ws,
    const float* __restrict__ bq, const float* __restrict__ bk1,
    const float* __restrict__ bk2, const float* __restrict__ bk3)
{
    const int rt = blockIdx.y, b = blockIdx.z, n0 = blockIdx.x * 128;
    const int t = threadIdx.x, w = t >> 6, lane = t & 63;
    const int m = lane & 15, q = lane >> 4;
    const int nw = n0 + w * 32;

    const ushort* W;
    const float* bias;
    int sel;
    ushort* dst;
    if (rt < 4) {
        W    = (const ushort*)(ws + ((rt==0)?OFF_WQ:(rt==1)?OFF_WK1:(rt==2)?OFF_WK2:OFF_WK3));
        bias = (rt==0)?bq:(rt==1)?bk1:(rt==2)?bk2:bk3;
        sel  = (rt==2) ? 1 : (rt==3) ? 2 : 0;
        dst  = (ushort*)(ws + ((rt==0)?OFF_QT:(rt==1)?OFF_K1T:(rt==2)?OFF_K2T:OFF_K3T))
               + (size_t)b * NN * CQd;
    } else {
        W    = (const ushort*)(ws + OFF_WU) + (size_t)(rt - 4) * 64 * CC;
        bias = (const float*)(ws + OFF_BU) + (rt - 4) * 64;
        sel  = 0;
        dst  = (ushort*)(ws + OFF_U) + (size_t)b * CC * NN + (size_t)(rt - 4) * 64 * NN;
    }
    const ushort* Bt = (const ushort*)(ws + OFF_XT) + ((size_t)sel * 2 + b) * NN * CC;
    const float bsc = (rt == 0) ? LOG2E : 1.0f;   // bq joins the exp2 fold

    const ushort* Ap = W + (size_t)m * CC + q * 8;
    const ushort* Bp = Bt + (size_t)(nw + m) * CC + q * 8;

    f32x4 acc[4][2];
#pragma unroll
    for (int i = 0; i < 4; ++i)
#pragma unroll
        for (int j = 0; j < 2; ++j) acc[i][j] = (f32x4)(0.f);

    short8 ab[2][4], bb[2][2];
    auto ld = [&](int s, int k) {
#pragma unroll
        for (int f = 0; f < 4; ++f)
            ab[s][f] = *(const short8*)(Ap + (size_t)f * 16 * CC + k);
#pragma unroll
        for (int g = 0; g < 2; ++g)
            bb[s][g] = *(const short8*)(Bp + (size_t)g * 16 * CC + k);
    };
    auto comp = [&](int s) {
#pragma unroll
        for (int mf = 0; mf < 4; ++mf)
#pragma unroll
            for (int nf = 0; nf < 2; ++nf)
                acc[mf][nf] = MFMA_BF16(ab[s][mf], bb[s][nf], acc[mf][nf]);
    };
    ld(0, 0); ld(1, 32);
    for (int i = 0; i < 16; i += 2) {
        comp(0); ld(0, ((i + 2 < 16) ? (i + 2) : 15) * 32);
        comp(1); ld(1, ((i + 3 < 16) ? (i + 3) : 15) * 32);
    }

    if (rt < 4) {   // transposed: dst[n][r]
#pragma unroll
        for (int mf = 0; mf < 4; ++mf) {
            const int r0 = mf * 16 + q * 4;
            const float b0 = bias[r0]*bsc, b1 = bias[r0+1]*bsc,
                        b2 = bias[r0+2]*bsc, b3 = bias[r0+3]*bsc;
#pragma unroll
            for (int nf = 0; nf < 2; ++nf) {
                const f32x4 v = acc[mf][nf];
                *(ushort4*)(dst + (size_t)(nw + nf*16 + m) * CQd + r0) =
                    pack4(v[0]+b0, v[1]+b1, v[2]+b2, v[3]+b3);
            }
        }
    } else {        // natural: dst[r][n]
#pragma unroll
        for (int mf = 0; mf < 4; ++mf) {
            const int r0 = mf * 16 + q * 4;
#pragma unroll
            for (int rr = 0; rr < 4; ++rr) {
                const float bo = bias[r0 + rr];
#pragma unroll
                for (int nf = 0; nf < 2; ++nf)
                    dst[(size_t)(r0 + rr) * NN + nw + nf*16 + m] = f2bf(acc[mf][nf][rr] + bo);
            }
        }
    }
}

// ---------------------------------------------------------------------------
// rowstats v6: Zpart[p=jq*4+w][br][b][i] = sum_{j slice} exp2(S'_br[i,j]).
// Wave owns 64 i x 32 j, sweeps 8 j-steps of 128 stride; dist-1 K prefetch
// with LITERAL buffer slots (2 steps x 3 br = 6 units unrolled per iter).
// grid (64 i-tiles, 4 jq, 2 b), block 256.
// ---------------------------------------------------------------------------
__global__ __launch_bounds__(256) void rowstats_k(
    const ushort* __restrict__ Qt, const ushort* __restrict__ K1t,
    const ushort* __restrict__ K2t, const ushort* __restrict__ K3t,
    float* __restrict__ Zpart)
{
    const int it = blockIdx.x, jq = blockIdx.y, b = blockIdx.z;
    const int t = threadIdx.x, w = t >> 6, lane = t & 63;
    const int m = lane & 15, quad = lane >> 4;
    const int i0 = it * 64;
    const int jbase = jq * 1024 + w * 32;

    const ushort* Qp  = Qt  + (size_t)b * NN * CQd;
    const ushort* Kp0 = K1t + (size_t)b * NN * CQd;
    const ushort* Kp1 = K2t + (size_t)b * NN * CQd;
    const ushort* Kp2 = K3t + (size_t)b * NN * CQd;

    short8 a[4][2];
#pragma unroll
    for (int mf = 0; mf < 4; ++mf) {
        const ushort* ap = Qp + (size_t)(i0 + mf * 16 + m) * CQd + quad * 8;
        a[mf][0] = *(const short8*)ap;
        a[mf][1] = *(const short8*)(ap + 32);
    }

    float z[3][4][4];
#pragma unroll
    for (int br = 0; br < 3; ++br)
#pragma unroll
        for (int mf = 0; mf < 4; ++mf)
#pragma unroll
            for (int r = 0; r < 4; ++r) z[br][mf][r] = 0.f;

    short8 kb[2][2][2];   // [slot][nf][half] -- only ever indexed with literals
    auto ldk = [&](int slot, int s, int br) {
        const ushort* Kb = (br == 0) ? Kp0 : (br == 1) ? Kp1 : Kp2;
#pragma unroll
        for (int nf = 0; nf < 2; ++nf) {
            const ushort* kp = Kb + (size_t)(jbase + s * 128 + nf * 16 + m) * CQd + quad * 8;
            kb[slot][nf][0] = *(const short8*)kp;
            kb[slot][nf][1] = *(const short8*)(kp + 32);
        }
    };
    auto comp = [&](int slot, int br) {
#pragma unroll
        for (int nf = 0; nf < 2; ++nf)
#pragma unroll
            for (int mf = 0; mf < 4; ++mf) {
                f32x4 sf = MFMA_BF16(a[mf][0], kb[slot][nf][0], (f32x4)(0.f));
                sf = MFMA_BF16(a[mf][1], kb[slot][nf][1], sf);
                z[br][mf][0] += exp2f(sf[0]);
                z[br][mf][1] += exp2f(sf[1]);
                z[br][mf][2] += exp2f(sf[2]);
                z[br][mf][3] += exp2f(sf[3]);
            }
    };

    ldk(0, 0, 0);
    for (int s2 = 0; s2 < 4; ++s2) {
        const int sA = s2 * 2, sB = s2 * 2 + 1;
        const int sN = (s2 < 3) ? s2 * 2 + 2 : 7;   // next pair's first step (clamped)
        ldk(1, sA, 1);  comp(0, 0);    // compute (sA,br0), prefetch (sA,br1)
        ldk(0, sA, 2);  comp(1, 1);    // compute (sA,br1), prefetch (sA,br2)
        ldk(1, sB, 0);  comp(0, 2);    // compute (sA,br2), prefetch (sB,br0)
        ldk(0, sB, 1);  comp(1, 0);    // compute (sB,br0), prefetch (sB,br1)
        ldk(1, sB, 2);  comp(0, 1);    // compute (sB,br1), prefetch (sB,br2)
        ldk(0, sN, 0);  comp(1, 2);    // compute (sB,br2), prefetch (sN,br0)
    }

    const int p = jq * 4 + w;
#pragma unroll
    for (int br = 0; br < 3; ++br)
#pragma unroll
        for (int mf = 0; mf < 4; ++mf)
#pragma unroll
            for (int r = 0; r < 4; ++r) {
                float v = z[br][mf][r];
                v += __shfl_xor(v, 1);
                v += __shfl_xor(v, 2);
                v += __shfl_xor(v, 4);
                v += __shfl_xor(v, 8);
                if (m == 0)
                    Zpart[(((size_t)p * 3 + br) * 2 + b) * NN + i0 + mf * 16 + quad * 4 + r] = v;
            }
}

// ---------------------------------------------------------------------------
// pmat: Pt[j][i] = sum_br exp2(S'_br[i,j]) / Z_br[i], bf16, dist-1 prefetch
// (u-loop fully unrolled -> literal slots), per-wave LDS transpose stores.
// grid (32 j-tiles of 128, 64 i-tiles of 64, 2 b), block 256.
// ---------------------------------------------------------------------------
__global__ __launch_bounds__(256) void pmat_k(
    const ushort* __restrict__ Qt, const ushort* __restrict__ K1t,
    const ushort* __restrict__ K2t, const ushort* __restrict__ K3t,
    const float* __restrict__ Zpart, ushort* __restrict__ Pt)
{
    const int j0 = blockIdx.x * 128, i0 = blockIdx.y * 64, b = blockIdx.z;
    const int t = threadIdx.x, w = t >> 6, lane = t & 63;
    const int m = lane & 15, quad = lane >> 4;
    const int jw = j0 + w * 32;

    __shared__ float zinv[3][64];
    __shared__ ushort pbuf[4][32][72];
    if (t < 192) {
        const int br = t >> 6, il = t & 63;
        float s = 0.f;
#pragma unroll
        for (int p = 0; p < 16; ++p)
            s += Zpart[(((size_t)p * 3 + br) * 2 + b) * NN + i0 + il];
        zinv[br][il] = 1.f / s;
    }
    __syncthreads();

    const ushort* Qp  = Qt  + (size_t)b * NN * CQd;
    const ushort* Kp0 = K1t + (size_t)b * NN * CQd;
    const ushort* Kp1 = K2t + (size_t)b * NN * CQd;
    const ushort* Kp2 = K3t + (size_t)b * NN * CQd;

    short8 a[4][2];
#pragma unroll
    for (int mf = 0; mf < 4; ++mf) {
        const ushort* ap = Qp + (size_t)(i0 + mf * 16 + m) * CQd + quad * 8;
        a[mf][0] = *(const short8*)ap;
        a[mf][1] = *(const short8*)(ap + 32);
    }

    f32x4 pacc[4][2];
#pragma unroll
    for (int mf = 0; mf < 4; ++mf)
#pragma unroll
        for (int nf = 0; nf < 2; ++nf) pacc[mf][nf] = (f32x4)(0.f);

    short8 kb[2][2];    // [slot][half]
    auto ldk = [&](int slot, int u) {
        const int br = u >> 1, nf = u & 1;
        const ushort* Kb = (br == 0) ? Kp0 : (br == 1) ? Kp1 : Kp2;
        const ushort* kp = Kb + (size_t)(jw + nf * 16 + m) * CQd + quad * 8;
        kb[slot][0] = *(const short8*)kp;
        kb[slot][1] = *(const short8*)(kp + 32);
    };

    ldk(0, 0);
    float rz[4][4];
#pragma unroll
    for (int u = 0; u < 6; ++u) {
        const int slot = u & 1;
        ldk(slot ^ 1, (u < 5) ? u + 1 : 5);
        const int br = u >> 1, nf = u & 1;
        if (nf == 0) {
#pragma unroll
            for (int mf = 0; mf < 4; ++mf)
#pragma unroll
                for (int r = 0; r < 4; ++r)
                    rz[mf][r] = zinv[br][mf * 16 + quad * 4 + r];
        }
#pragma unroll
        for (int mf = 0; mf < 4; ++mf) {
            f32x4 sf = MFMA_BF16(a[mf][0], kb[slot][0], (f32x4)(0.f));
            sf = MFMA_BF16(a[mf][1], kb[slot][1], sf);
            pacc[mf][nf][0] += exp2f(sf[0]) * rz[mf][0];
            pacc[mf][nf][1] += exp2f(sf[1]) * rz[mf][1];
            pacc[mf][nf][2] += exp2f(sf[2]) * rz[mf][2];
            pacc[mf][nf][3] += exp2f(sf[3]) * rz[mf][3];
        }
    }

#pragma unroll
    for (int mf = 0; mf < 4; ++mf)
#pragma unroll
        for (int nf = 0; nf < 2; ++nf) {
            const f32x4 v = pacc[mf][nf];
            *(ushort4*)&pbuf[w][nf * 16 + m][mf * 16 + quad * 4] = pack4(v[0], v[1], v[2], v[3]);
        }
    ushort* Pb = Pt + (size_t)b * NN * NN;
#pragma unroll
    for (int p = 0; p < 4; ++p) {
        const int row = p * 8 + (lane >> 3);
        const int c16 = lane & 7;
        const uint4 v = *(const uint4*)&pbuf[w][row][c16 * 8];
        *(uint4*)(Pb + (size_t)(jw + row) * NN + i0 + c16 * 8) = v;
    }
}

// ---------------------------------------------------------------------------
// av: Part[h][b][c][j] = (U[:, h-half] @ P[h-half, :]) bf16.  m97 structure:
// 128x128 tile, BK=64, global_load_lds(16B) staging, ds_read_b128 frags.
// grid (32 j, 4 c, 4 = b*2+h), block 256 (4 waves, 64x64 each). LDS 32 KB.
// ---------------------------------------------------------------------------
__global__ __launch_bounds__(256) void av_k(
    const ushort* __restrict__ U, const ushort* __restrict__ Pt,
    ushort* __restrict__ Part)
{
    const int t = threadIdx.x, w = t >> 6, lane = t & 63;
    const int m = lane & 15, q = lane >> 4;
    const int zz = blockIdx.z;
    const int b = zz >> 1, h = zz & 1;
    const int j0 = blockIdx.x * 128;
    const int c0 = blockIdx.y * 128;
    const int k00 = h * 2048;

    __shared__ ushort As[128][64];   // [c-local][k-local]
    __shared__ ushort Bs[128][64];   // [j-local][k-local]

    const ushort* Ub = U + (size_t)b * CC * NN;
    const ushort* Pb = Pt + (size_t)b * NN * NN;

    const int srow = w * 32 + (lane >> 3);
    const int scol = (lane & 7) * 8;
    const ushort* gA = Ub + (size_t)(c0 + srow) * NN + k00 + scol;
    const ushort* gB = Pb + (size_t)(j0 + srow) * NN + k00 + scol;

    const int cw = (w >> 1) * 64, jw = (w & 1) * 64;

    f32x4 acc[4][4];
#pragma unroll
    for (int i = 0; i < 4; ++i)
#pragma unroll
        for (int j = 0; j < 4; ++j) acc[i][j] = (f32x4)(0.f);

    for (int k0 = 0; k0 < 2048; k0 += 64) {
        __syncthreads();
#pragma unroll
        for (int i2 = 0; i2 < 4; ++i2) {
            gll16(gA + (size_t)i2 * 8 * NN + k0, &As[w * 32 + i2 * 8][0]);
            gll16(gB + (size_t)i2 * 8 * NN + k0, &Bs[w * 32 + i2 * 8][0]);
        }
        __syncthreads();
#pragma unroll
        for (int kk = 0; kk < 2; ++kk) {
            short8 af[4], bf[4];
#pragma unroll
            for (int f = 0; f < 4; ++f) {
                af[f] = *(const short8*)&As[cw + f * 16 + m][kk * 32 + q * 8];
                bf[f] = *(const short8*)&Bs[jw + f * 16 + m][kk * 32 + q * 8];
            }
#pragma unroll
            for (int mf = 0; mf < 4; ++mf)
#pragma unroll
                for (int nf = 0; nf < 4; ++nf)
                    acc[mf][nf] = MFMA_BF16(af[mf], bf[nf], acc[mf][nf]);
        }
    }

    ushort* Pp = Part + ((size_t)h * 2 + b) * CC * NN;
#pragma unroll
    for (int mf = 0; mf < 4; ++mf) {
        const int r0 = c0 + cw + mf * 16 + q * 4;
#pragma unroll
        for (int nf = 0; nf < 4; ++nf) {
            const int col = j0 + jw + nf * 16 + m;
            const f32x4 v = acc[mf][nf];
            Pp[(size_t)(r0 + 0) * NN + col] = f2bf(v[0]);
            Pp[(size_t)(r0 + 1) * NN + col] = f2bf(v[1]);
            Pp[(size_t)(r0 + 2) * NN + col] = f2bf(v[2]);
            Pp[(size_t)(r0 + 3) * NN + col] = f2bf(v[3]);
        }
    }
}

// ---------------------------------------------------------------------------
// fin: out = x + gamma*(Part0 + Part1 + bl).  grid (1024 rows, 4), block 256.
// ---------------------------------------------------------------------------
__global__ __launch_bounds__(256) void fin_k(
    const ushort* __restrict__ Part, const float* __restrict__ x,
    const float* __restrict__ bl, const float* __restrict__ gam,
    float* __restrict__ out)
{
    const int row = blockIdx.x;                 // b*512 + c
    const int b = row >> 9, c = row & 511;
    const int col = blockIdx.y * 1024 + threadIdx.x * 4;
    const float g = gam[0];
    const float bo = bl[c];
    const size_t base = ((size_t)b * CC + c) * NN + col;
    const ushort4 p0 = *(const ushort4*)(Part + ((size_t)b * CC + c) * NN + col);
    const ushort4 p1 = *(const ushort4*)(Part + ((size_t)(2 + b) * CC + c) * NN + col);
    const float4 xv = *(const float4*)(x + base);
    float4 o;
    o.x = xv.x + g * (bf2f(p0.x) + bf2f(p1.x) + bo);
    o.y = xv.y + g * (bf2f(p0.y) + bf2f(p1.y) + bo);
    o.z = xv.z + g * (bf2f(p0.z) + bf2f(p1.z) + bo);
    o.w = xv.w + g * (bf2f(p0.w) + bf2f(p1.w) + bo);
    *(float4*)(out + base) = o;
}

// ---------------------------------------------------------------------------
extern "C" void kernel_launch(void* const* d_in, const int* in_sizes, int n_in,
                              void* d_out, int out_size, void* d_ws, size_t ws_size,
                              hipStream_t stream)
{
    (void)in_sizes; (void)n_in; (void)out_size; (void)ws_size;

    const float* xp  = (const float*)d_in[0];
    const float* yp  = (const float*)d_in[1];
    const float* zp  = (const float*)d_in[2];
    const float* Wq  = (const float*)d_in[3];
    const float* bq  = (const float*)d_in[4];
    const float* Wk1 = (const float*)d_in[5];
    const float* bk1 = (const float*)d_in[6];
    const float* Wk2 = (const float*)d_in[7];
    const float* bk2 = (const float*)d_in[8];
    const float* Wk3 = (const float*)d_in[9];
    const float* bk3 = (const float*)d_in[10];
    const float* Wv  = (const float*)d_in[11];
    const float* bv  = (const float*)d_in[12];
    const float* Wl  = (const float*)d_in[13];
    const float* bl  = (const float*)d_in[14];
    const float* gam = (const float*)d_in[15];
    float* out = (float*)d_out;

    char* ws = (char*)d_ws;
    ushort* WVT = (ushort*)(ws + OFF_WVT);
    ushort* WU  = (ushort*)(ws + OFF_WU);
    float*  BU  = (float*)(ws + OFF_BU);
    const ushort* QT  = (const ushort*)(ws + OFF_QT);
    const ushort* K1T = (const ushort*)(ws + OFF_K1T);
    const ushort* K2T = (const ushort*)(ws + OFF_K2T);
    const ushort* K3T = (const ushort*)(ws + OFF_K3T);
    const ushort* Ub  = (const ushort*)(ws + OFF_U);
    float*  ZP  = (float*)(ws + OFF_Z);
    ushort* PT  = (ushort*)(ws + OFF_PT);
    ushort* XT  = (ushort*)(ws + OFF_XT);
    ushort* PRT = (ushort*)(ws + OFF_PART);

    cast_k<<<dim3(256, 5), 256, 0, stream>>>(Wq, Wk1, Wk2, Wk3, Wl, ws);
    wvt_k<<<dim3(8, 8), 256, 0, stream>>>(Wv, WVT);
    transpose_k<<<dim3(64, 8, 6), 256, 0, stream>>>(xp, yp, zp, XT);
    bu_k<<<dim3(8), 256, 0, stream>>>(Wl, bv, BU);
    wlwv_k<<<dim3(8, 8), 256, 0, stream>>>((const ushort*)(ws + OFF_WLB), WVT, WU);
    projU_k<<<dim3(32, 12, 2), 256, 0, stream>>>(ws, bq, bk1, bk2, bk3);
    rowstats_k<<<dim3(64, 4, 2), 256, 0, stream>>>(QT, K1T, K2T, K3T, ZP);
    pmat_k<<<dim3(32, 64, 2), 256, 0, stream>>>(QT, K1T, K2T, K3T, ZP, PT);
    av_k<<<dim3(32, 4, 4), 256, 0, stream>>>(Ub, PT, PRT);
    fin_k<<<dim3(1024, 4), 256, 0, stream>>>(PRT, xp, bl, gam, out);
}

// Round 8
// 312.456 us; speedup vs baseline: 1.2047x; 1.0158x over previous
//
#include <hip/hip_runtime.h>

// MsPAM all-MFMA v7b.
// Algebra: out = x + gamma*(U@P + bl), U = (Wl@Wv)@x + Wl@bv,
//          P = sum_br softmax_rows(Q^T K_br)  (transposed-softmax semantics).
// v7b: EXP2 = __builtin_amdgcn_exp2f (bare v_exp_f32; v7's __exp2f collided
//      with glibc host decl), pbuf pad 72->76 (kills 8-way transpose-store
//      conflicts), cast/wvt/bu merged into one prep kernel.
// MFMA 16x16x32 bf16 layouts: A[m=lane&15][k=quad*8+j], B[n=lane&15][k=quad*8+j],
// C/D col=lane&15, row=quad*4+reg.

typedef __attribute__((ext_vector_type(8))) short short8;
typedef __attribute__((ext_vector_type(4))) float f32x4;
#define MFMA_BF16(a,b,c) __builtin_amdgcn_mfma_f32_16x16x32_bf16((a),(b),(c),0,0,0)
#define EXP2(x) __builtin_amdgcn_exp2f(x)   // single v_exp_f32; |S'|<~15, no fixup needed

#define NN 4096
#define CC 512
#define CQd 64
#define LOG2E 1.4426950408889634f

// ---- workspace byte offsets ------------------------------------------------
#define OFF_WQ   ((size_t)0)          // 64x512 bf16   65536  (pre-scaled by log2e)
#define OFF_WK1  ((size_t)65536)
#define OFF_WK2  ((size_t)131072)
#define OFF_WK3  ((size_t)196608)
#define OFF_WLB  ((size_t)262144)     // Wl bf16 512x512   524288
#define OFF_WVT  ((size_t)786432)     // Wv^T bf16 [i][c]  524288
#define OFF_WU   ((size_t)1310720)    // Wl@Wv bf16 [o][i] 524288
#define OFF_BU   ((size_t)1835008)    // Wl@bv fp32 [512]  2048
#define OFF_QT   ((size_t)1837056)    // [2][4096][64] bf16, 1 MB each
#define OFF_K1T  ((size_t)2885632)
#define OFF_K2T  ((size_t)3934208)
#define OFF_K3T  ((size_t)4982784)
#define OFF_U    ((size_t)6031360)    // U bf16 [2][512][4096]  8 MB
#define OFF_Z    ((size_t)14419968)   // Zpart f32 [16][3][2][4096] = 1,572,864
#define OFF_PT   ((size_t)15992832)   // Pt bf16 [2][4096][4096] 64 MB -> end 83,101,696
// xT/yT/zT bf16 [3][2][4096][512] alias the TAIL of Pt (dead before pmat writes Pt)
#define OFF_XT   ((size_t)57935872)
#define OFF_PART ((size_t)83101696)   // bf16 [2 ksplit][2 b][512][4096] 16 MB -> end 99,878,912

__device__ __forceinline__ unsigned short f2bf(float f) {
    unsigned int u = __float_as_uint(f);
    u = u + 0x7FFFu + ((u >> 16) & 1u);   // RNE
    return (unsigned short)(u >> 16);
}
__device__ __forceinline__ ushort4 pack4(float a, float b, float c, float d) {
    return make_ushort4(f2bf(a), f2bf(b), f2bf(c), f2bf(d));
}
__device__ __forceinline__ float bf2f(unsigned short u) {
    return __uint_as_float(((unsigned int)u) << 16);
}
// async global->LDS, 16B per lane; LDS dest = wave-uniform base + lane*16.
__device__ __forceinline__ void gll16(const void* g, void* l) {
    __builtin_amdgcn_global_load_lds(
        (const __attribute__((address_space(1))) void*)g,
        (__attribute__((address_space(3))) void*)l, 16, 0, 0);
}

// ---------------------------------------------------------------------------
// prep: flat grid 1352 blocks x 256.
//   id <  1280: cast Wq,Wk1,Wk2,Wk3,Wl fp32->bf16 (Wq scaled by log2e)
//   id <  1344: WvT transpose (fp32 [c][i] -> bf16 [i][c])
//   id == 1344..1351: bU = Wl @ bv
// ---------------------------------------------------------------------------
__global__ __launch_bounds__(256) void prep_k(
    const float* __restrict__ Wq, const float* __restrict__ Wk1, const float* __restrict__ Wk2,
    const float* __restrict__ Wk3, const float* __restrict__ Wl, const float* __restrict__ Wv,
    const float* __restrict__ bv, char* __restrict__ ws)
{
    const int id = blockIdx.x;
    const int t = threadIdx.x;
    if (id < 1280) {
        const int y = id / 256, bx = id % 256;
        const float* src = (y==0)?Wq:(y==1)?Wk1:(y==2)?Wk2:(y==3)?Wk3:Wl;
        const size_t off = (y==0)?OFF_WQ:(y==1)?OFF_WK1:(y==2)?OFF_WK2:(y==3)?OFF_WK3:OFF_WLB;
        ushort* dst = (ushort*)(ws + off);
        const int size = (y < 4) ? (CQd*CC) : (CC*CC);
        const float sc = (y == 0) ? LOG2E : 1.0f;
        const int idx = (bx * 256 + t) * 4;
        if (idx < size) {
            const float4 v = *(const float4*)(src + idx);
            *(ushort4*)(dst + idx) = pack4(v.x*sc, v.y*sc, v.z*sc, v.w*sc);
        }
    } else if (id < 1344) {
        const int idx = id - 1280;
        const int i0 = (idx & 7) * 64, c0 = (idx >> 3) * 64;
        ushort* WvT = (ushort*)(ws + OFF_WVT);
        __shared__ float tile[64][65];
        const int tr = t >> 6, tc = t & 63;
#pragma unroll
        for (int p = 0; p < 16; ++p) {
            const int r = p * 4 + tr;
            tile[r][tc] = Wv[(size_t)(c0 + r) * CC + i0 + tc];
        }
        __syncthreads();
#pragma unroll
        for (int p = 0; p < 16; ++p) {
            const int ir = p * 4 + tr;
            WvT[(size_t)(i0 + ir) * CC + c0 + tc] = f2bf(tile[tc][ir]);
        }
    } else {
        const int o0 = (id - 1344) * 64;
        float* bU = (float*)(ws + OFF_BU);
        const int r = t >> 2, seg = t & 3;
        const float* wp = Wl + (size_t)(o0 + r) * CC + seg * 128;
        const float* vp = bv + seg * 128;
        float s = 0.f;
#pragma unroll 8
        for (int c = 0; c < 128; c += 4) {
            const float4 wv = *(const float4*)(wp + c);
            const float4 bb = *(const float4*)(vp + c);
            s += wv.x*bb.x + wv.y*bb.y + wv.z*bb.z + wv.w*bb.w;
        }
        __shared__ float red[64][4];
        red[r][seg] = s;
        __syncthreads();
        if (t < 64) bU[o0 + t] = red[t][0] + red[t][1] + red[t][2] + red[t][3];
    }
}

// ---------------------------------------------------------------------------
// transpose x,y,z fp32 [b][c][n] -> bf16 [n][c].  grid (64, 8, 6), block 256.
// ---------------------------------------------------------------------------
__global__ __launch_bounds__(256) void transpose_k(
    const float* __restrict__ x, const float* __restrict__ y, const float* __restrict__ z,
    ushort* __restrict__ xt_base)
{
    const int zi = blockIdx.z;
    const int s = zi >> 1, b = zi & 1;
    const float* src = ((s==0) ? x : (s==1) ? y : z) + (size_t)b * CC * NN;
    ushort* dst = xt_base + (size_t)s * 2 * NN * CC + (size_t)b * NN * CC;
    const int n0 = blockIdx.x * 64, c0 = blockIdx.y * 64;
    __shared__ float tile[64][65];
    const int t = threadIdx.x, tr = t >> 6, tc = t & 63;
#pragma unroll
    for (int p = 0; p < 16; ++p) {
        const int r = p * 4 + tr;
        tile[r][tc] = src[(size_t)(c0 + r) * NN + n0 + tc];
    }
    __syncthreads();
#pragma unroll
    for (int p = 0; p < 16; ++p) {
        const int nr = p * 4 + tr;
        dst[(size_t)(n0 + nr) * CC + c0 + tc] = f2bf(tile[tc][nr]);
    }
}

// ---------------------------------------------------------------------------
// WU = WlB @ WvT^T  (bf16 out [o][i]).  grid (8,8), block 256, wave 32x32.
// ---------------------------------------------------------------------------
__global__ __launch_bounds__(256) void wlwv_k(
    const ushort* __restrict__ WlB, const ushort* __restrict__ WvT, ushort* __restrict__ WU)
{
    const int n0 = blockIdx.x * 64, o0 = blockIdx.y * 64;
    const int t = threadIdx.x, w = t >> 6, lane = t & 63;
    const int m = lane & 15, q = lane >> 4;
    const int ow = o0 + (w >> 1) * 32, nw = n0 + (w & 1) * 32;

    const ushort* Ap = WlB + (size_t)(ow + m) * CC + q * 8;
    const ushort* Bp = WvT + (size_t)(nw + m) * CC + q * 8;

    f32x4 acc[2][2];
#pragma unroll
    for (int i = 0; i < 2; ++i)
#pragma unroll
        for (int j = 0; j < 2; ++j) acc[i][j] = (f32x4)(0.f);

    short8 ab[2][2], bb[2][2];
    auto ld = [&](int s, int k) {
#pragma unroll
        for (int f = 0; f < 2; ++f) {
            ab[s][f] = *(const short8*)(Ap + (size_t)f * 16 * CC + k);
            bb[s][f] = *(const short8*)(Bp + (size_t)f * 16 * CC + k);
        }
    };
    auto comp = [&](int s) {
#pragma unroll
        for (int mf = 0; mf < 2; ++mf)
#pragma unroll
            for (int nf = 0; nf < 2; ++nf)
                acc[mf][nf] = MFMA_BF16(ab[s][mf], bb[s][nf], acc[mf][nf]);
    };
    ld(0, 0); ld(1, 32);
    for (int i = 0; i < 16; i += 2) {
        comp(0); ld(0, ((i + 2 < 16) ? (i + 2) : 15) * 32);
        comp(1); ld(1, ((i + 3 < 16) ? (i + 3) : 15) * 32);
    }
#pragma unroll
    for (int mf = 0; mf < 2; ++mf)
#pragma unroll
        for (int nf = 0; nf < 2; ++nf) {
            const int col = nw + nf * 16 + m;
#pragma unroll
            for (int rr = 0; rr < 4; ++rr)
                WU[(size_t)(ow + mf * 16 + q * 4 + rr) * CC + col] = f2bf(acc[mf][nf][rr]);
        }
}

// ---------------------------------------------------------------------------
// unified projection: rows of [Q;K1;K2;K3;U] = W @ src(+bias).
// rt 0..3 -> Q/K1/K2/K3 (transposed bf16 out [n][64]); rt 4..11 -> U rows.
// grid (32 n-tiles(128), 12, 2), block 256, wave 64r x 32n, K=512.
// ---------------------------------------------------------------------------
__global__ __launch_bounds__(256) void projU_k(
    const char* __restrict__ ws,
    const float* __restrict__ bq, const float* __restrict__ bk1,
    const float* __restrict__ bk2, const float* __restrict__ bk3)
{
    const int rt = blockIdx.y, b = blockIdx.z, n0 = blockIdx.x * 128;
    const int t = threadIdx.x, w = t >> 6, lane = t & 63;
    const int m = lane & 15, q = lane >> 4;
    const int nw = n0 + w * 32;

    const ushort* W;
    const float* bias;
    int sel;
    ushort* dst;
    if (rt < 4) {
        W    = (const ushort*)(ws + ((rt==0)?OFF_WQ:(rt==1)?OFF_WK1:(rt==2)?OFF_WK2:OFF_WK3));
        bias = (rt==0)?bq:(rt==1)?bk1:(rt==2)?bk2:bk3;
        sel  = (rt==2) ? 1 : (rt==3) ? 2 : 0;
        dst  = (ushort*)(ws + ((rt==0)?OFF_QT:(rt==1)?OFF_K1T:(rt==2)?OFF_K2T:OFF_K3T))
               + (size_t)b * NN * CQd;
    } else {
        W    = (const ushort*)(ws + OFF_WU) + (size_t)(rt - 4) * 64 * CC;
        bias = (const float*)(ws + OFF_BU) + (rt - 4) * 64;
        sel  = 0;
        dst  = (ushort*)(ws + OFF_U) + (size_t)b * CC * NN + (size_t)(rt - 4) * 64 * NN;
    }
    const ushort* Bt = (const ushort*)(ws + OFF_XT) + ((size_t)sel * 2 + b) * NN * CC;
    const float bsc = (rt == 0) ? LOG2E : 1.0f;   // bq joins the exp2 fold

    const ushort* Ap = W + (size_t)m * CC + q * 8;
    const ushort* Bp = Bt + (size_t)(nw + m) * CC + q * 8;

    f32x4 acc[4][2];
#pragma unroll
    for (int i = 0; i < 4; ++i)
#pragma unroll
        for (int j = 0; j < 2; ++j) acc[i][j] = (f32x4)(0.f);

    short8 ab[2][4], bb[2][2];
    auto ld = [&](int s, int k) {
#pragma unroll
        for (int f = 0; f < 4; ++f)
            ab[s][f] = *(const short8*)(Ap + (size_t)f * 16 * CC + k);
#pragma unroll
        for (int g = 0; g < 2; ++g)
            bb[s][g] = *(const short8*)(Bp + (size_t)g * 16 * CC + k);
    };
    auto comp = [&](int s) {
#pragma unroll
        for (int mf = 0; mf < 4; ++mf)
#pragma unroll
            for (int nf = 0; nf < 2; ++nf)
                acc[mf][nf] = MFMA_BF16(ab[s][mf], bb[s][nf], acc[mf][nf]);
    };
    ld(0, 0); ld(1, 32);
    for (int i = 0; i < 16; i += 2) {
        comp(0); ld(0, ((i + 2 < 16) ? (i + 2) : 15) * 32);
        comp(1); ld(1, ((i + 3 < 16) ? (i + 3) : 15) * 32);
    }

    if (rt < 4) {   // transposed: dst[n][r]
#pragma unroll
        for (int mf = 0; mf < 4; ++mf) {
            const int r0 = mf * 16 + q * 4;
            const float b0 = bias[r0]*bsc, b1 = bias[r0+1]*bsc,
                        b2 = bias[r0+2]*bsc, b3 = bias[r0+3]*bsc;
#pragma unroll
            for (int nf = 0; nf < 2; ++nf) {
                const f32x4 v = acc[mf][nf];
                *(ushort4*)(dst + (size_t)(nw + nf*16 + m) * CQd + r0) =
                    pack4(v[0]+b0, v[1]+b1, v[2]+b2, v[3]+b3);
            }
        }
    } else {        // natural: dst[r][n]
#pragma unroll
        for (int mf = 0; mf < 4; ++mf) {
            const int r0 = mf * 16 + q * 4;
#pragma unroll
            for (int rr = 0; rr < 4; ++rr) {
                const float bo = bias[r0 + rr];
#pragma unroll
                for (int nf = 0; nf < 2; ++nf)
                    dst[(size_t)(r0 + rr) * NN + nw + nf*16 + m] = f2bf(acc[mf][nf][rr] + bo);
            }
        }
    }
}

// ---------------------------------------------------------------------------
// rowstats: Zpart[p=jq*4+w][br][b][i] = sum_{j slice} exp2(S'_br[i,j]).
// Wave owns 64 i x 32 j, sweeps 8 j-steps of 128 stride; dist-1 K prefetch
// with LITERAL buffer slots (2 steps x 3 br = 6 units unrolled per iter).
// grid (64 i-tiles, 4 jq, 2 b), block 256.
// ---------------------------------------------------------------------------
__global__ __launch_bounds__(256) void rowstats_k(
    const ushort* __restrict__ Qt, const ushort* __restrict__ K1t,
    const ushort* __restrict__ K2t, const ushort* __restrict__ K3t,
    float* __restrict__ Zpart)
{
    const int it = blockIdx.x, jq = blockIdx.y, b = blockIdx.z;
    const int t = threadIdx.x, w = t >> 6, lane = t & 63;
    const int m = lane & 15, quad = lane >> 4;
    const int i0 = it * 64;
    const int jbase = jq * 1024 + w * 32;

    const ushort* Qp  = Qt  + (size_t)b * NN * CQd;
    const ushort* Kp0 = K1t + (size_t)b * NN * CQd;
    const ushort* Kp1 = K2t + (size_t)b * NN * CQd;
    const ushort* Kp2 = K3t + (size_t)b * NN * CQd;

    short8 a[4][2];
#pragma unroll
    for (int mf = 0; mf < 4; ++mf) {
        const ushort* ap = Qp + (size_t)(i0 + mf * 16 + m) * CQd + quad * 8;
        a[mf][0] = *(const short8*)ap;
        a[mf][1] = *(const short8*)(ap + 32);
    }

    float z[3][4][4];
#pragma unroll
    for (int br = 0; br < 3; ++br)
#pragma unroll
        for (int mf = 0; mf < 4; ++mf)
#pragma unroll
            for (int r = 0; r < 4; ++r) z[br][mf][r] = 0.f;

    short8 kb[2][2][2];   // [slot][nf][half] -- only ever indexed with literals
    auto ldk = [&](int slot, int s, int br) {
        const ushort* Kb = (br == 0) ? Kp0 : (br == 1) ? Kp1 : Kp2;
#pragma unroll
        for (int nf = 0; nf < 2; ++nf) {
            const ushort* kp = Kb + (size_t)(jbase + s * 128 + nf * 16 + m) * CQd + quad * 8;
            kb[slot][nf][0] = *(const short8*)kp;
            kb[slot][nf][1] = *(const short8*)(kp + 32);
        }
    };
    auto comp = [&](int slot, int br) {
#pragma unroll
        for (int nf = 0; nf < 2; ++nf)
#pragma unroll
            for (int mf = 0; mf < 4; ++mf) {
                f32x4 sf = MFMA_BF16(a[mf][0], kb[slot][nf][0], (f32x4)(0.f));
                sf = MFMA_BF16(a[mf][1], kb[slot][nf][1], sf);
                z[br][mf][0] += EXP2(sf[0]);
                z[br][mf][1] += EXP2(sf[1]);
                z[br][mf][2] += EXP2(sf[2]);
                z[br][mf][3] += EXP2(sf[3]);
            }
    };

    ldk(0, 0, 0);
    for (int s2 = 0; s2 < 4; ++s2) {
        const int sA = s2 * 2, sB = s2 * 2 + 1;
        const int sN = (s2 < 3) ? s2 * 2 + 2 : 7;   // next pair's first step (clamped)
        ldk(1, sA, 1);  comp(0, 0);    // compute (sA,br0), prefetch (sA,br1)
        ldk(0, sA, 2);  comp(1, 1);    // compute (sA,br1), prefetch (sA,br2)
        ldk(1, sB, 0);  comp(0, 2);    // compute (sA,br2), prefetch (sB,br0)
        ldk(0, sB, 1);  comp(1, 0);    // compute (sB,br0), prefetch (sB,br1)
        ldk(1, sB, 2);  comp(0, 1);    // compute (sB,br1), prefetch (sB,br2)
        ldk(0, sN, 0);  comp(1, 2);    // compute (sB,br2), prefetch (sN,br0)
    }

    const int p = jq * 4 + w;
#pragma unroll
    for (int br = 0; br < 3; ++br)
#pragma unroll
        for (int mf = 0; mf < 4; ++mf)
#pragma unroll
            for (int r = 0; r < 4; ++r) {
                float v = z[br][mf][r];
                v += __shfl_xor(v, 1);
                v += __shfl_xor(v, 2);
                v += __shfl_xor(v, 4);
                v += __shfl_xor(v, 8);
                if (m == 0)
                    Zpart[(((size_t)p * 3 + br) * 2 + b) * NN + i0 + mf * 16 + quad * 4 + r] = v;
            }
}

// ---------------------------------------------------------------------------
// pmat: Pt[j][i] = sum_br exp2(S'_br[i,j]) / Z_br[i], bf16, dist-1 prefetch
// (u-loop fully unrolled -> literal slots), per-wave LDS transpose stores.
// grid (32 j-tiles of 128, 64 i-tiles of 64, 2 b), block 256.
// ---------------------------------------------------------------------------
__global__ __launch_bounds__(256) void pmat_k(
    const ushort* __restrict__ Qt, const ushort* __restrict__ K1t,
    const ushort* __restrict__ K2t, const ushort* __restrict__ K3t,
    const float* __restrict__ Zpart, ushort* __restrict__ Pt)
{
    const int j0 = blockIdx.x * 128, i0 = blockIdx.y * 64, b = blockIdx.z;
    const int t = threadIdx.x, w = t >> 6, lane = t & 63;
    const int m = lane & 15, quad = lane >> 4;
    const int jw = j0 + w * 32;

    __shared__ float zinv[3][64];
    __shared__ ushort pbuf[4][32][76];   // 76: stride 38 dwords -> conflict-free walk
    if (t < 192) {
        const int br = t >> 6, il = t & 63;
        float s = 0.f;
#pragma unroll
        for (int p = 0; p < 16; ++p)
            s += Zpart[(((size_t)p * 3 + br) * 2 + b) * NN + i0 + il];
        zinv[br][il] = 1.f / s;
    }
    __syncthreads();

    const ushort* Qp  = Qt  + (size_t)b * NN * CQd;
    const ushort* Kp0 = K1t + (size_t)b * NN * CQd;
    const ushort* Kp1 = K2t + (size_t)b * NN * CQd;
    const ushort* Kp2 = K3t + (size_t)b * NN * CQd;

    short8 a[4][2];
#pragma unroll
    for (int mf = 0; mf < 4; ++mf) {
        const ushort* ap = Qp + (size_t)(i0 + mf * 16 + m) * CQd + quad * 8;
        a[mf][0] = *(const short8*)ap;
        a[mf][1] = *(const short8*)(ap + 32);
    }

    f32x4 pacc[4][2];
#pragma unroll
    for (int mf = 0; mf < 4; ++mf)
#pragma unroll
        for (int nf = 0; nf < 2; ++nf) pacc[mf][nf] = (f32x4)(0.f);

    short8 kb[2][2];    // [slot][half]
    auto ldk = [&](int slot, int u) {
        const int br = u >> 1, nf = u & 1;
        const ushort* Kb = (br == 0) ? Kp0 : (br == 1) ? Kp1 : Kp2;
        const ushort* kp = Kb + (size_t)(jw + nf * 16 + m) * CQd + quad * 8;
        kb[slot][0] = *(const short8*)kp;
        kb[slot][1] = *(const short8*)(kp + 32);
    };

    ldk(0, 0);
    float rz[4][4];
#pragma unroll
    for (int u = 0; u < 6; ++u) {
        const int slot = u & 1;
        ldk(slot ^ 1, (u < 5) ? u + 1 : 5);
        const int br = u >> 1, nf = u & 1;
        if (nf == 0) {
#pragma unroll
            for (int mf = 0; mf < 4; ++mf)
#pragma unroll
                for (int r = 0; r < 4; ++r)
                    rz[mf][r] = zinv[br][mf * 16 + quad * 4 + r];
        }
#pragma unroll
        for (int mf = 0; mf < 4; ++mf) {
            f32x4 sf = MFMA_BF16(a[mf][0], kb[slot][0], (f32x4)(0.f));
            sf = MFMA_BF16(a[mf][1], kb[slot][1], sf);
            pacc[mf][nf][0] += EXP2(sf[0]) * rz[mf][0];
            pacc[mf][nf][1] += EXP2(sf[1]) * rz[mf][1];
            pacc[mf][nf][2] += EXP2(sf[2]) * rz[mf][2];
            pacc[mf][nf][3] += EXP2(sf[3]) * rz[mf][3];
        }
    }

#pragma unroll
    for (int mf = 0; mf < 4; ++mf)
#pragma unroll
        for (int nf = 0; nf < 2; ++nf) {
            const f32x4 v = pacc[mf][nf];
            *(ushort4*)&pbuf[w][nf * 16 + m][mf * 16 + quad * 4] = pack4(v[0], v[1], v[2], v[3]);
        }
    ushort* Pb = Pt + (size_t)b * NN * NN;
#pragma unroll
    for (int p = 0; p < 4; ++p) {
        const int row = p * 8 + (lane >> 3);
        const int c16 = lane & 7;
        const uint4 v = *(const uint4*)&pbuf[w][row][c16 * 8];
        *(uint4*)(Pb + (size_t)(jw + row) * NN + i0 + c16 * 8) = v;
    }
}

// ---------------------------------------------------------------------------
// av: Part[h][b][c][j] = (U[:, h-half] @ P[h-half, :]) bf16.  m97 structure:
// 128x128 tile, BK=64, global_load_lds(16B) staging, ds_read_b128 frags.
// grid (32 j, 4 c, 4 = b*2+h), block 256 (4 waves, 64x64 each). LDS 32 KB.
// ---------------------------------------------------------------------------
__global__ __launch_bounds__(256) void av_k(
    const ushort* __restrict__ U, const ushort* __restrict__ Pt,
    ushort* __restrict__ Part)
{
    const int t = threadIdx.x, w = t >> 6, lane = t & 63;
    const int m = lane & 15, q = lane >> 4;
    const int zz = blockIdx.z;
    const int b = zz >> 1, h = zz & 1;
    const int j0 = blockIdx.x * 128;
    const int c0 = blockIdx.y * 128;
    const int k00 = h * 2048;

    __shared__ ushort As[128][64];   // [c-local][k-local]
    __shared__ ushort Bs[128][64];   // [j-local][k-local]

    const ushort* Ub = U + (size_t)b * CC * NN;
    const ushort* Pb = Pt + (size_t)b * NN * NN;

    const int srow = w * 32 + (lane >> 3);
    const int scol = (lane & 7) * 8;
    const ushort* gA = Ub + (size_t)(c0 + srow) * NN + k00 + scol;
    const ushort* gB = Pb + (size_t)(j0 + srow) * NN + k00 + scol;

    const int cw = (w >> 1) * 64, jw = (w & 1) * 64;

    f32x4 acc[4][4];
#pragma unroll
    for (int i = 0; i < 4; ++i)
#pragma unroll
        for (int j = 0; j < 4; ++j) acc[i][j] = (f32x4)(0.f);

    for (int k0 = 0; k0 < 2048; k0 += 64) {
        __syncthreads();
#pragma unroll
        for (int i2 = 0; i2 < 4; ++i2) {
            gll16(gA + (size_t)i2 * 8 * NN + k0, &As[w * 32 + i2 * 8][0]);
            gll16(gB + (size_t)i2 * 8 * NN + k0, &Bs[w * 32 + i2 * 8][0]);
        }
        __syncthreads();
#pragma unroll
        for (int kk = 0; kk < 2; ++kk) {
            short8 af[4], bf[4];
#pragma unroll
            for (int f = 0; f < 4; ++f) {
                af[f] = *(const short8*)&As[cw + f * 16 + m][kk * 32 + q * 8];
                bf[f] = *(const short8*)&Bs[jw + f * 16 + m][kk * 32 + q * 8];
            }
#pragma unroll
            for (int mf = 0; mf < 4; ++mf)
#pragma unroll
                for (int nf = 0; nf < 4; ++nf)
                    acc[mf][nf] = MFMA_BF16(af[mf], bf[nf], acc[mf][nf]);
        }
    }

    ushort* Pp = Part + ((size_t)h * 2 + b) * CC * NN;
#pragma unroll
    for (int mf = 0; mf < 4; ++mf) {
        const int r0 = c0 + cw + mf * 16 + q * 4;
#pragma unroll
        for (int nf = 0; nf < 4; ++nf) {
            const int col = j0 + jw + nf * 16 + m;
            const f32x4 v = acc[mf][nf];
            Pp[(size_t)(r0 + 0) * NN + col] = f2bf(v[0]);
            Pp[(size_t)(r0 + 1) * NN + col] = f2bf(v[1]);
            Pp[(size_t)(r0 + 2) * NN + col] = f2bf(v[2]);
            Pp[(size_t)(r0 + 3) * NN + col] = f2bf(v[3]);
        }
    }
}

// ---------------------------------------------------------------------------
// fin: out = x + gamma*(Part0 + Part1 + bl).  grid (1024 rows, 4), block 256.
// ---------------------------------------------------------------------------
__global__ __launch_bounds__(256) void fin_k(
    const ushort* __restrict__ Part, const float* __restrict__ x,
    const float* __restrict__ bl, const float* __restrict__ gam,
    float* __restrict__ out)
{
    const int row = blockIdx.x;                 // b*512 + c
    const int b = row >> 9, c = row & 511;
    const int col = blockIdx.y * 1024 + threadIdx.x * 4;
    const float g = gam[0];
    const float bo = bl[c];
    const size_t base = ((size_t)b * CC + c) * NN + col;
    const ushort4 p0 = *(const ushort4*)(Part + ((size_t)b * CC + c) * NN + col);
    const ushort4 p1 = *(const ushort4*)(Part + ((size_t)(2 + b) * CC + c) * NN + col);
    const float4 xv = *(const float4*)(x + base);
    float4 o;
    o.x = xv.x + g * (bf2f(p0.x) + bf2f(p1.x) + bo);
    o.y = xv.y + g * (bf2f(p0.y) + bf2f(p1.y) + bo);
    o.z = xv.z + g * (bf2f(p0.z) + bf2f(p1.z) + bo);
    o.w = xv.w + g * (bf2f(p0.w) + bf2f(p1.w) + bo);
    *(float4*)(out + base) = o;
}

// ---------------------------------------------------------------------------
extern "C" void kernel_launch(void* const* d_in, const int* in_sizes, int n_in,
                              void* d_out, int out_size, void* d_ws, size_t ws_size,
                              hipStream_t stream)
{
    (void)in_sizes; (void)n_in; (void)out_size; (void)ws_size;

    const float* xp  = (const float*)d_in[0];
    const float* yp  = (const float*)d_in[1];
    const float* zp  = (const float*)d_in[2];
    const float* Wq  = (const float*)d_in[3];
    const float* bq  = (const float*)d_in[4];
    const float* Wk1 = (const float*)d_in[5];
    const float* bk1 = (const float*)d_in[6];
    const float* Wk2 = (const float*)d_in[7];
    const float* bk2 = (const float*)d_in[8];
    const float* Wk3 = (const float*)d_in[9];
    const float* bk3 = (const float*)d_in[10];
    const float* Wv  = (const float*)d_in[11];
    const float* bv  = (const float*)d_in[12];
    const float* Wl  = (const float*)d_in[13];
    const float* bl  = (const float*)d_in[14];
    const float* gam = (const float*)d_in[15];
    float* out = (float*)d_out;

    char* ws = (char*)d_ws;
    ushort* WVT = (ushort*)(ws + OFF_WVT);
    ushort* WU  = (ushort*)(ws + OFF_WU);
    const ushort* QT  = (const ushort*)(ws + OFF_QT);
    const ushort* K1T = (const ushort*)(ws + OFF_K1T);
    const ushort* K2T = (const ushort*)(ws + OFF_K2T);
    const ushort* K3T = (const ushort*)(ws + OFF_K3T);
    const ushort* Ub  = (const ushort*)(ws + OFF_U);
    float*  ZP  = (float*)(ws + OFF_Z);
    ushort* PT  = (ushort*)(ws + OFF_PT);
    ushort* XT  = (ushort*)(ws + OFF_XT);
    ushort* PRT = (ushort*)(ws + OFF_PART);

    prep_k<<<dim3(1352), 256, 0, stream>>>(Wq, Wk1, Wk2, Wk3, Wl, Wv, bv, ws);
    transpose_k<<<dim3(64, 8, 6), 256, 0, stream>>>(xp, yp, zp, XT);
    wlwv_k<<<dim3(8, 8), 256, 0, stream>>>((const ushort*)(ws + OFF_WLB), WVT, WU);
    projU_k<<<dim3(32, 12, 2), 256, 0, stream>>>(ws, bq, bk1, bk2, bk3);
    rowstats_k<<<dim3(64, 4, 2), 256, 0, stream>>>(QT, K1T, K2T, K3T, ZP);
    pmat_k<<<dim3(32, 64, 2), 256, 0, stream>>>(QT, K1T, K2T, K3T, ZP, PT);
    av_k<<<dim3(32, 4, 4), 256, 0, stream>>>(Ub, PT, PRT);
    fin_k<<<dim3(1024, 4), 256, 0, stream>>>(PRT, xp, bl, gam, out);
}